// Round 11
// baseline (429.400 us; speedup 1.0000x reference)
//
#include <hip/hip_runtime.h>
#include <hip/hip_cooperative_groups.h>
#include <stdint.h>

#define B_ 256
#define H_ 600
#define W_ 19
#define C1_ 40
#define C2_ 40
#define KH_ 29
#define PAD_ 14
#define NW_ 760       // C1_*W_
#define NWORDS_ 12    // ceil(760/64)
#define NJ_ 39
#define FIN_ 1560     // C2_*NJ_
#define FOUT_ 80
#define FCW_ 25       // ceil(1560/64)
#define HS1 300       // h rows per P1 block-half
#define XSTL2 332     // LDS column stride in floats (16B-aligned columns)

typedef float vf4 __attribute__((ext_vector_type(4)));

struct Pargs {
  const float *x,*w1,*g1,*b1,*m1,*v1,*w2,*g2,*b2,*m2,*v2,*a2,
              *fc1w,*g3,*b3,*m3,*v3,*a3,*fc2w;
  float *w1s,*bnp,*out;
  uint64_t *w2m,*fc1p,*s1b;
  int8_t *fc2s,*sp;
};

union alignas(16) SharedU {
  float xs[W_ * XSTL2];                                              // P1: 25.2 KB
  struct { float z[20][601]; uint64_t w2l[20][NWORDS_]; float bnl[80]; } p2;  // 50.3 KB
  struct { uint64_t spP[FCW_], spN[FCW_]; int z3[FOUT_]; } p3;       // 0.7 KB
};

// bnp layout: [0:40) s1, [40:80) t1, [80:120) s2, [120:160) t2, [160:240) s3, [240:320) t3
// s1b layout: [b][wd][h] ulonglong2 {P, M}; bit idx within plane = w*40 + c1
__global__ __launch_bounds__(256, 2) void fused(Pargs P)
{
  cooperative_groups::grid_group grid = cooperative_groups::this_grid();
  __shared__ SharedU sh;
  const int bid = blockIdx.x, tid = threadIdx.x;
  const int lane = tid & 63, wave = tid >> 6;

  // ================= P0: weight/bn preprocessing =================
  {
    int t0 = bid*256 + tid, np = 512*256;
    int gw = bid*4 + wave,  nw = 512*4;
    for (int i = t0; i < C1_*KH_; i += np){
      float v = P.w1[i];
      P.w1s[i] = (v > 0.f) ? 1.f : ((v < 0.f) ? -1.f : 0.f);
    }
    for (int v = gw; v < C2_*NWORDS_; v += nw){          // w2 pos plane (never 0)
      int c2 = v / NWORDS_, wd = v % NWORDS_;
      int idx = wd*64 + lane;
      float val = 0.f;
      if (idx < NW_){ int c1 = idx % 40, w = idx / 40; val = P.w2[c2*NW_ + c1*W_ + w]; }
      unsigned long long m = __ballot(val > 0.f);
      if (lane == 0) P.w2m[c2*NWORDS_ + wd] = m;
    }
    for (int v = gw; v < FOUT_*2*FCW_; v += nw){         // fc1 pos/neg planes
      int o = v / (2*FCW_), r = v % (2*FCW_);
      int neg = r / FCW_, wd = r % FCW_;
      int e = wd*64 + lane;
      float val = (e < FIN_) ? P.fc1w[o*FIN_ + e] : 0.f;
      unsigned long long m = __ballot(neg ? (val < 0.f) : (val > 0.f));
      if (lane == 0) P.fc1p[o*(2*FCW_) + r] = m;
    }
    for (int i = t0; i < 2*FOUT_; i += np){
      float v = P.fc2w[i]; P.fc2s[i] = (int8_t)((v > 0.f) - (v < 0.f));
    }
    for (int i = t0; i < C1_; i += np){
      float s = __fdiv_rn(P.g1[i], __fsqrt_rn(__fadd_rn(P.v1[i], 1e-5f)));
      P.bnp[i] = s; P.bnp[40+i] = __fsub_rn(P.b1[i], __fmul_rn(P.m1[i], s));
    }
    for (int i = t0; i < C2_; i += np){
      float s = __fdiv_rn(P.g2[i], __fsqrt_rn(__fadd_rn(P.v2[i], 1e-5f)));
      P.bnp[80+i] = s; P.bnp[120+i] = __fsub_rn(P.b2[i], __fmul_rn(P.m2[i], s));
    }
    for (int i = t0; i < FOUT_; i += np){
      float s = __fdiv_rn(P.g3[i], __fsqrt_rn(__fadd_rn(P.v3[i], 1e-5f)));
      P.bnp[160+i] = s; P.bnp[240+i] = __fsub_rn(P.b3[i], __fmul_rn(P.m3[i], s));
    }
  }
  grid.sync();

  // ================= P1: conv1 + bn1 + sign (ballot-packed) =================
  // Per 4-output group: 8 ds_read_b128 -> ONE volatile pin of 8 float4 tuples ->
  // 4x29 FMA chains (ascending k, bit-exact). Pinned tuples can't be remat'd;
  // nothing lives across the group back-edge -> no scratch.
  {
    int b = bid >> 1, ht = bid & 1;
    int h0 = HS1 * ht;
    const float* xb = P.x + (size_t)b * H_ * W_;
    for (int i = tid; i < (HS1 + 28) * W_; i += 256){
      int r = i / W_, w = i % W_;
      int gh = h0 - PAD_ + r;
      sh.xs[w*XSTL2 + r] = (gh >= 0 && gh < H_) ? xb[gh*W_ + w] : 0.f;
    }
    __syncthreads();

    #pragma unroll 1
    for (int rd = 0; rd < 3; ++rd){
      int wd  = rd*4 + wave;                 // this wave's bit-word (0..11)
      int idx = wd*64 + lane;
      bool valid = (idx < NW_);
      int c1 = idx % 40;
      int w  = valid ? (idx / 40) : 18;

      float wt[KH_];
      #pragma unroll
      for (int k = 0; k < KH_; ++k) wt[k] = P.w1s[c1*KH_ + k];
      float scale = P.bnp[c1], bias = P.bnp[40 + c1];
      if (!valid){ scale = __builtin_nanf(""); bias = scale; }  // NaN => ballots false
      const float* xcol = &sh.xs[w * XSTL2];
      ulonglong2* ob = (ulonglong2*)P.s1b + ((size_t)(b*12 + wd) * H_ + h0);

      #pragma unroll 1
      for (int n = 0; n < 75; ++n){                      // 75 groups x 4 outputs = 300
        const vf4* xq = (const vf4*)xcol + n;            // rows 4n..4n+31
        vf4 q0=xq[0],q1=xq[1],q2=xq[2],q3=xq[3],q4=xq[4],q5=xq[5],q6=xq[6],q7=xq[7];
        asm volatile("" : "+v"(q0),"+v"(q1),"+v"(q2),"+v"(q3),
                          "+v"(q4),"+v"(q5),"+v"(q6),"+v"(q7));
        float xv[32];
        #pragma unroll
        for (int j = 0; j < 4; ++j){
          xv[j]=q0[j]; xv[4+j]=q1[j]; xv[8+j]=q2[j];  xv[12+j]=q3[j];
          xv[16+j]=q4[j]; xv[20+j]=q5[j]; xv[24+j]=q6[j]; xv[28+j]=q7[j];
        }
        float a0=0.f, a1=0.f, a2=0.f, a3=0.f;
        #pragma unroll
        for (int k = 0; k < 29; ++k){
          float wk = wt[k];
          a0 = __builtin_fmaf(wk, xv[k],   a0);          // ascending k: bit-exact
          a1 = __builtin_fmaf(wk, xv[k+1], a1);
          a2 = __builtin_fmaf(wk, xv[k+2], a2);
          a3 = __builtin_fmaf(wk, xv[k+3], a3);
        }
        float z0 = __fadd_rn(__fmul_rn(a0, scale), bias);  // sign(prelu)==sign
        float z1 = __fadd_rn(__fmul_rn(a1, scale), bias);
        float z2 = __fadd_rn(__fmul_rn(a2, scale), bias);
        float z3 = __fadd_rn(__fmul_rn(a3, scale), bias);
        unsigned long long bp0=__ballot(z0>0.f), bm0=__ballot(z0<0.f);
        unsigned long long bp1=__ballot(z1>0.f), bm1=__ballot(z1<0.f);
        unsigned long long bp2=__ballot(z2>0.f), bm2=__ballot(z2<0.f);
        unsigned long long bp3=__ballot(z3>0.f), bm3=__ballot(z3<0.f);
        if (lane == 0){
          ulonglong2 t;
          t.x = bp0; t.y = bp0 | bm0; ob[4*n+0] = t;
          t.x = bp1; t.y = bp1 | bm1; ob[4*n+1] = t;
          t.x = bp2; t.y = bp2 | bm2; ob[4*n+2] = t;
          t.x = bp3; t.y = bp3 | bm3; ob[4*n+3] = t;
        }
      }
    }
  }
  grid.sync();

  // ================= P2: conv2 + bn2 + prelu + avgpool-sign =================
  {
    int b = bid >> 1, half = bid & 1;
    for (int i = tid; i < 20*NWORDS_; i += 256)
      ((uint64_t*)sh.p2.w2l)[i] = P.w2m[half*20*NWORDS_ + i];
    for (int i = tid; i < 80; i += 256) sh.p2.bnl[i] = P.bnp[80 + i];
    __syncthreads();

    float alpha2 = P.a2[0];
    const ulonglong2* sb = (const ulonglong2*)P.s1b + (size_t)b * NWORDS_ * H_;
    #pragma unroll 1
    for (int ps = 0; ps < 3; ++ps){
      int row = ps*256 + tid;
      if (row < H_){
        uint64_t Pv[NWORDS_], Mv[NWORDS_];
        #pragma unroll
        for (int wd = 0; wd < NWORDS_; ++wd){
          ulonglong2 pm = sb[(size_t)wd * H_ + row];     // coalesced: lane=row
          Pv[wd] = pm.x; Mv[wd] = pm.y;
        }
        int nzv = 0;
        #pragma unroll
        for (int wd = 0; wd < NWORDS_; ++wd) nzv += __popcll(Mv[wd]);
        #pragma unroll 2
        for (int cl = 0; cl < 20; ++cl){
          int c2 = half*20 + cl;
          int dsum = 0;
          #pragma unroll
          for (int wd = 0; wd < NWORDS_; ++wd)
            dsum += __popcll(Mv[wd] & (Pv[wd] ^ sh.p2.w2l[cl][wd]));  // LDS broadcast
          int y = nzv - 2*dsum;
          float u = __fadd_rn(__fmul_rn((float)y, sh.p2.bnl[c2]), sh.p2.bnl[40 + c2]);
          sh.p2.z[cl][row] = (u >= 0.f) ? u : __fmul_rn(alpha2, u);
        }
      }
    }
    __syncthreads();
    for (int o = tid; o < 20*NJ_; o += 256){             // sign(sum/30)==sign(sum)
      int cl = o / NJ_, j = o % NJ_;
      int base = 15*j;
      float s = 0.f;
      #pragma unroll
      for (int r = 0; r < 30; ++r) s = __fadd_rn(s, sh.p2.z[cl][base + r]);  // ascending
      P.sp[(size_t)b*FIN_ + (half*20 + cl)*NJ_ + j] = (int8_t)((s > 0.f) - (s < 0.f));
    }
  }
  grid.sync();

  // ================= P3: fc1 popcount + bn3 + prelu + sign + fc2 =================
  if (bid < B_){
    int b = bid;
    const int8_t* spb = P.sp + (size_t)b * FIN_;
    for (int wd = wave; wd < FCW_; wd += 4){
      int e = wd*64 + lane;
      int v = (e < FIN_) ? (int)spb[e] : 0;
      unsigned long long pp = __ballot(v > 0);
      unsigned long long nn = __ballot(v < 0);
      if (lane == 0){ sh.p3.spP[wd] = pp; sh.p3.spN[wd] = nn; }
    }
    __syncthreads();
    float alpha3 = P.a3[0];
    if (tid < FOUT_){
      const uint64_t* wp = P.fc1p + tid * (2*FCW_);
      int acc = 0;
      #pragma unroll
      for (int wd = 0; wd < FCW_; ++wd){
        uint64_t Pp = sh.p3.spP[wd], Nn = sh.p3.spN[wd];
        acc += __popcll(Pp & wp[wd]) + __popcll(Nn & wp[FCW_ + wd])
             - __popcll(Pp & wp[FCW_ + wd]) - __popcll(Nn & wp[wd]);
      }
      float u = __fadd_rn(__fmul_rn((float)acc, P.bnp[160 + tid]), P.bnp[240 + tid]);
      float zz = (u >= 0.f) ? u : __fmul_rn(alpha3, u);
      sh.p3.z3[tid] = (zz > 0.f) - (zz < 0.f);
    }
    __syncthreads();
    if (tid < 2){
      int acc = 0;
      for (int o = 0; o < FOUT_; ++o) acc += sh.p3.z3[o] * (int)P.fc2s[tid*FOUT_ + o];
      P.out[b*2 + tid] = (float)acc;
    }
  }
}

extern "C" void kernel_launch(void* const* d_in, const int* in_sizes, int n_in,
                              void* d_out, int out_size, void* d_ws, size_t ws_size,
                              hipStream_t stream)
{
  char* ws = (char*)d_ws;
  Pargs hp;
  hp.x    = (const float*)d_in[0];
  hp.w1   = (const float*)d_in[1];
  hp.g1   = (const float*)d_in[2];
  hp.b1   = (const float*)d_in[3];
  hp.m1   = (const float*)d_in[4];
  hp.v1   = (const float*)d_in[5];
  // d_in[6] (a1) unused: prelu is sign-invariant before the binarize
  hp.w2   = (const float*)d_in[7];
  hp.g2   = (const float*)d_in[8];
  hp.b2   = (const float*)d_in[9];
  hp.m2   = (const float*)d_in[10];
  hp.v2   = (const float*)d_in[11];
  hp.a2   = (const float*)d_in[12];
  hp.fc1w = (const float*)d_in[13];
  hp.g3   = (const float*)d_in[14];
  hp.b3   = (const float*)d_in[15];
  hp.m3   = (const float*)d_in[16];
  hp.v3   = (const float*)d_in[17];
  hp.a3   = (const float*)d_in[18];
  hp.fc2w = (const float*)d_in[19];

  hp.s1b  = (uint64_t*)(ws);               // 256*12*600*16 = 29,491,200 B
  hp.w2m  = (uint64_t*)(ws + 29491200);    // 3,840 B
  hp.w1s  = (float*)   (ws + 29495040);    // 4,640 B
  hp.bnp  = (float*)   (ws + 29499680);    // 1,280 B
  hp.fc1p = (uint64_t*)(ws + 29500960);    // 32,000 B
  hp.fc2s = (int8_t*)  (ws + 29532960);    // 160 B
  hp.sp   = (int8_t*)  (ws + 29533120);    // 399,360 B
  hp.out  = (float*)d_out;

  void* args[] = { &hp };
  hipLaunchCooperativeKernel(reinterpret_cast<void*>(fused),
                             dim3(512), dim3(256), args, 0, stream);
}